// Round 3
// baseline (527.324 us; speedup 1.0000x reference)
//
#include <hip/hip_runtime.h>
#include <math.h>

#define NB 4
#define C 96
#define C3 288
#define NH 8
#define CHD 12
#define HT 160
#define WD 160
#define HW 25600

typedef unsigned short u16;
typedef unsigned int   u32;

__device__ __forceinline__ float gelu_f(float x){
    return 0.5f * x * (1.0f + erff(x * 0.7071067811865475f));
}
__device__ __forceinline__ float sigmoid_f(float x){
    return 1.0f / (1.0f + expf(-x));
}
__device__ __forceinline__ u16 f2bf(float x){
    union { float f; u32 u; } v; v.f = x;
    u32 r = v.u + 0x7FFFu + ((v.u >> 16) & 1u);
    return (u16)(r >> 16);
}
__device__ __forceinline__ float bf2f(u16 s){
    union { u32 u; float f; } v; v.u = ((u32)s) << 16;
    return v.f;
}

// ---------------- K0: per-(b,c) spatial sums of x + bf16 copy of x ----------
__global__ __launch_bounds__(256) void k0_xsum(const float* __restrict__ x,
                                               float* __restrict__ xsum,
                                               u16* __restrict__ xb){
    int bc = blockIdx.x;                       // 0..383
    const float4* p4 = (const float4*)(x + (size_t)bc * HW);
    u32* xo = (u32*)(xb + (size_t)bc * HW);
    float s = 0.f;
    for (int i = threadIdx.x; i < HW/4; i += 256){
        float4 v = p4[i];
        s += (v.x + v.y) + (v.z + v.w);
        xo[i*2]   = (u32)f2bf(v.x) | ((u32)f2bf(v.y) << 16);
        xo[i*2+1] = (u32)f2bf(v.z) | ((u32)f2bf(v.w) << 16);
    }
    __shared__ float red[256];
    red[threadIdx.x] = s;
    __syncthreads();
    for (int off = 128; off > 0; off >>= 1){
        if (threadIdx.x < off) red[threadIdx.x] += red[threadIdx.x + off];
        __syncthreads();
    }
    if (threadIdx.x == 0) xsum[bc] = red[0];
}

// ---------------- K1: all tiny per-batch math --------------------------------
__global__ void k1_small(const float* __restrict__ spectral, const float* __restrict__ xsum,
                         const float* __restrict__ w_se1, const float* __restrict__ b_se1,
                         const float* __restrict__ w_se2, const float* __restrict__ b_se2,
                         const float* __restrict__ w_saw1, const float* __restrict__ b_saw1,
                         const float* __restrict__ w_saw2, const float* __restrict__ b_saw2,
                         const float* __restrict__ w_sgp, const float* __restrict__ b_sgp,
                         const float* __restrict__ w_qkv,
                         float* __restrict__ swg, float* __restrict__ esgg,
                         float* __restrict__ weff){
    __shared__ float spec[96];
    __shared__ float h1[192];
    __shared__ float sw[96];
    __shared__ float cm_s;
    __shared__ float g1[9][24];
    __shared__ float saw[8];
    __shared__ float redbuf[96];
    int t = threadIdx.x;
    for (int b = 0; b < NB; b++){
        if (t < 96) spec[t] = spectral[b*96 + t];
        __syncthreads();
        if (t < 192){
            float a = b_se1[t];
            for (int c = 0; c < 96; c++) a += spec[c] * w_se1[t*96 + c];
            h1[t] = gelu_f(a);
        }
        __syncthreads();
        if (t < 96){
            float a = b_se2[t];
            for (int j = 0; j < 192; j++) a += h1[j] * w_se2[t*192 + j];
            float s = sigmoid_f(a);
            sw[t] = s;
            swg[b*96 + t] = s;
            redbuf[t] = s * xsum[b*96 + t];
        }
        __syncthreads();
        if (t == 0){
            float cs = 0.f;
            for (int c = 0; c < 96; c++) cs += redbuf[c];
            cm_s = cs / (96.0f * (float)HW);
        }
        __syncthreads();
        float cm = cm_s;
        if (t < 9*24){
            int cat = t / 24, ch = t % 24;
            int ti = cat / 3, tj = cat % 3;
            float S = 0.f;
            for (int ki = 0; ki < 3; ki++){
                if (ti == 0 && ki == 0) continue;
                if (ti == 2 && ki == 2) continue;
                for (int kj = 0; kj < 3; kj++){
                    if (tj == 0 && kj == 0) continue;
                    if (tj == 2 && kj == 2) continue;
                    S += w_saw1[ch*9 + ki*3 + kj];
                }
            }
            g1[cat][ch] = gelu_f(cm * S + b_saw1[ch]);
        }
        __syncthreads();
        if (t < 8){
            float acc = 0.f;
            const float cnt[3] = {1.f, 158.f, 1.f};
            for (int cat = 0; cat < 9; cat++){
                float a = b_saw2[t];
                for (int ch = 0; ch < 24; ch++) a += w_saw2[t*24 + ch] * g1[cat][ch];
                acc += cnt[cat/3] * cnt[cat%3] * sigmoid_f(a);
            }
            saw[t] = acc / (float)HW;
        }
        __syncthreads();
        if (t < 96){
            float a = b_sgp[t];
            for (int j = 0; j < 96; j++) a += spec[j] * w_sgp[t*96 + j];
            esgg[b*96 + t] = a * saw[t/12];
        }
        for (int i = t; i < C3*96; i += 256){
            weff[(size_t)b*C3*96 + i] = w_qkv[i] * sw[i % 96];
        }
        __syncthreads();
    }
}

// ---------------- K2a: 1x1 conv (Weff @ x) one batch, bf16 in/out ------------
__global__ __launch_bounds__(256) void k2a_qkv(const u16* __restrict__ xb,
                                               const float* __restrict__ weff,
                                               u16* __restrict__ Y, int b){
    int oc0 = blockIdx.y * 24;
    int px = blockIdx.x * 1024 + threadIdx.x * 4;
    __shared__ float wsm[24*96];
    for (int i = threadIdx.x; i < 24*96; i += 256)
        wsm[i] = weff[((size_t)b*C3 + oc0)*96 + i];
    __syncthreads();
    const u32* xbp = (const u32*)(xb + (size_t)b*C*HW);
    float acc[24][4];
    #pragma unroll
    for (int i = 0; i < 24; i++) acc[i][0]=acc[i][1]=acc[i][2]=acc[i][3]=0.f;
    for (int c = 0; c < 96; c++){
        u32 v0 = xbp[((size_t)c*HW + px) >> 1];
        u32 v1 = xbp[(((size_t)c*HW + px) >> 1) + 1];
        float x0 = bf2f((u16)(v0 & 0xffffu)), x1 = bf2f((u16)(v0 >> 16));
        float x2 = bf2f((u16)(v1 & 0xffffu)), x3 = bf2f((u16)(v1 >> 16));
        #pragma unroll
        for (int i = 0; i < 24; i++){
            float w = wsm[i*96 + c];
            acc[i][0] += w*x0; acc[i][1] += w*x1;
            acc[i][2] += w*x2; acc[i][3] += w*x3;
        }
    }
    u32* Yo = (u32*)Y;
    #pragma unroll
    for (int i = 0; i < 24; i++){
        u32 p0 = (u32)f2bf(acc[i][0]) | ((u32)f2bf(acc[i][1]) << 16);
        u32 p1 = (u32)f2bf(acc[i][2]) | ((u32)f2bf(acc[i][3]) << 16);
        size_t o = ((size_t)(oc0+i)*HW + px) >> 1;
        Yo[o] = p0; Yo[o+1] = p1;
    }
}

// ---------------- K2b: 3x3 depthwise, Y bf16 -> qkv bf16 ---------------------
__global__ __launch_bounds__(256) void k2b_dw(const u16* __restrict__ Y,
                                              const float* __restrict__ w_dw,
                                              u16* __restrict__ qkv, int b){
    int ch = blockIdx.y;
    int r0 = blockIdx.x * 8;
    __shared__ float tile[10*160];
    const u16* Yc = Y + (size_t)ch*HW;
    for (int i = threadIdx.x; i < 800; i += 256){
        int r = i / 80, c2 = (i % 80) * 2;
        int gr = r0 + r - 1;
        u32 v = 0;
        if (gr >= 0 && gr < HT) v = *(const u32*)(Yc + gr*WD + c2);
        tile[r*160 + c2]   = bf2f((u16)(v & 0xffffu));
        tile[r*160 + c2+1] = bf2f((u16)(v >> 16));
    }
    float w[9];
    #pragma unroll
    for (int k = 0; k < 9; k++) w[k] = w_dw[ch*9 + k];
    __syncthreads();
    u16* qc = qkv + ((size_t)b*C3 + ch)*HW + r0*WD;
    for (int i = threadIdx.x; i < 640; i += 256){
        int r = i / 80, c2 = (i % 80) * 2;
        float a0 = 0.f, a1 = 0.f;
        #pragma unroll
        for (int ki = 0; ki < 3; ki++){
            const float* row = &tile[(r+ki)*160];
            #pragma unroll
            for (int kj = 0; kj < 3; kj++){
                float wv = w[ki*3+kj];
                int cc0 = c2 + kj - 1;
                int cc1 = cc0 + 1;
                if (cc0 >= 0 && cc0 < WD) a0 += wv * row[cc0];
                if (cc1 >= 0 && cc1 < WD) a1 += wv * row[cc1];
            }
        }
        u32 pk = (u32)f2bf(a0) | ((u32)f2bf(a1) << 16);
        *(u32*)(qc + r*WD + c2) = pk;
    }
}

// ---------------- K3: fc branch -> fws PLANAR (b,108,hw) bf16 ----------------
// f[d*9+o](n) = b_fc[o] + sum_g w_fc[o,g] * qkvflat[b][n*288 + g*12 + d]
__global__ __launch_bounds__(256) void k3_fc(const u16* __restrict__ qkv,
                                             const float* __restrict__ w_fc,
                                             const float* __restrict__ b_fc,
                                             u16* __restrict__ fws){
    int b  = blockIdx.y;
    int n0 = blockIdx.x * 32;
    __shared__ u16 r[32*289];
    __shared__ u16 ot[108*33];
    __shared__ float wfc[216];
    __shared__ float bfc[9];
    int t = threadIdx.x;
    if (t < 216) wfc[t] = w_fc[t];
    if (t < 9)   bfc[t] = b_fc[t];
    const u32* src = (const u32*)(qkv + (size_t)b*C3*HW + (size_t)n0*288);
    for (int i = t; i < 32*144; i += 256){
        u32 v = src[i];
        int row = i / 144, cc = (i % 144) * 2;
        r[row*289 + cc]     = (u16)(v & 0xffffu);
        r[row*289 + cc + 1] = (u16)(v >> 16);
    }
    __syncthreads();
    for (int col = t; col < 384; col += 256){
        int nl = col / 12, d = col % 12;
        float rv[24];
        #pragma unroll
        for (int g = 0; g < 24; g++) rv[g] = bf2f(r[nl*289 + g*12 + d]);
        #pragma unroll
        for (int o = 0; o < 9; o++){
            float a = bfc[o];
            #pragma unroll
            for (int g = 0; g < 24; g++) a += wfc[o*24 + g] * rv[g];
            ot[(d*9 + o)*33 + nl] = f2bf(a);
        }
    }
    __syncthreads();
    for (int i = t; i < 108*16; i += 256){
        int pl = i / 16, p2 = (i % 16) * 2;
        u32 pk = (u32)ot[pl*33 + p2] | ((u32)ot[pl*33 + p2 + 1] << 16);
        *(u32*)(fws + ((size_t)(b*108 + pl))*HW + n0 + p2) = pk;
    }
}

// ---------------- K4: Gram partials G[c,d]=sum_n q_c k_d, plus norms ---------
__global__ __launch_bounds__(256) void k4_gram(const u16* __restrict__ qkv,
                                               float* __restrict__ gpart){
    int b = blockIdx.z;
    int h = blockIdx.y;
    int t = threadIdx.x;
    __shared__ float qs[12*268];
    __shared__ float ks[12*268];
    const u32* qu = (const u32*)(qkv + ((size_t)b*C3 + h*CHD)*HW + blockIdx.x*1024);
    const u32* ku = (const u32*)(qkv + ((size_t)b*C3 + C + h*CHD)*HW + blockIdx.x*1024);
    float acc = 0.f;
    for (int sc = 0; sc < 4; sc++){
        __syncthreads();
        for (int i = t; i < 12*128; i += 256){
            int rr = i / 128, pu = i % 128;
            u32 qv = qu[rr*(HW/2) + sc*128 + pu];
            u32 kv = ku[rr*(HW/2) + sc*128 + pu];
            qs[rr*268 + 2*pu]     = bf2f((u16)(qv & 0xffffu));
            qs[rr*268 + 2*pu + 1] = bf2f((u16)(qv >> 16));
            ks[rr*268 + 2*pu]     = bf2f((u16)(kv & 0xffffu));
            ks[rr*268 + 2*pu + 1] = bf2f((u16)(kv >> 16));
        }
        __syncthreads();
        if (t < 144){
            int c = t / 12, d = t % 12;
            const float* qq = &qs[c*268];
            const float* kk = &ks[d*268];
            float a = 0.f;
            for (int p = 0; p < 256; p += 4){
                float4 q4 = *(const float4*)(qq + p);
                float4 k4 = *(const float4*)(kk + p);
                a += q4.x*k4.x + q4.y*k4.y + q4.z*k4.z + q4.w*k4.w;
            }
            acc += a;
        } else if (t < 168){
            int c = (t - 144) % 12;
            const float* qq = (t < 156) ? &qs[c*268] : &ks[c*268];
            float a = 0.f;
            for (int p = 0; p < 256; p += 4){
                float4 q4 = *(const float4*)(qq + p);
                a += q4.x*q4.x + q4.y*q4.y + q4.z*q4.z + q4.w*q4.w;
            }
            acc += a;
        }
    }
    if (t < 168)
        gpart[(((size_t)b*NH + h)*25 + blockIdx.x)*168 + t] = acc;
}

// ---------------- K5: softmax + M[b] = W_proj @ blockdiag(attn) --------------
__global__ void k5_attn(const float* __restrict__ gpart, const float* __restrict__ esgg,
                        const float* __restrict__ temp, const float* __restrict__ w_proj,
                        float* __restrict__ Mm){
    int b = blockIdx.x;
    int t = threadIdx.x;
    __shared__ float G[NH][144];
    __shared__ float q2[NH][12], k2[NH][12];
    __shared__ float attn[NH][144];
    for (int i = t; i < NH*168; i += 256){
        int h = i / 168, e = i % 168;
        float a = 0.f;
        for (int ch = 0; ch < 25; ch++)
            a += gpart[(((size_t)b*NH + h)*25 + ch)*168 + e];
        if (e < 144)      G[h][e] = a;
        else if (e < 156) q2[h][e-144] = a;
        else              k2[h][e-156] = a;
    }
    __syncthreads();
    if (t < 96){
        int h = t / 12, c = t % 12;
        float rq  = 1.0f / fmaxf(sqrtf(q2[h][c]), 1e-12f);
        float tm  = temp[h];
        float egc = esgg[b*96 + h*12 + c];
        float lo[12];
        float mx = -1e30f;
        for (int d = 0; d < 12; d++){
            float rk = 1.0f / fmaxf(sqrtf(k2[h][d]), 1e-12f);
            float v = G[h][c*12 + d] * rq * rk * tm * (egc * esgg[b*96 + h*12 + d]);
            lo[d] = v;
            mx = fmaxf(mx, v);
        }
        float s = 0.f;
        for (int d = 0; d < 12; d++){ lo[d] = expf(lo[d] - mx); s += lo[d]; }
        float inv = 1.0f / s;
        for (int d = 0; d < 12; d++) attn[h][c*12 + d] = lo[d] * inv;
    }
    __syncthreads();
    for (int i = t; i < 96*96; i += 256){
        int co = i / 96, ci = i % 96;
        int h = ci / 12, d = ci % 12;
        float a = 0.f;
        #pragma unroll
        for (int c = 0; c < 12; c++)
            a += w_proj[co*96 + h*12 + c] * attn[h][c*12 + d];
        Mm[((size_t)b*96 + co)*96 + ci] = a;
    }
}

// ---------------- K6a: grouped 3x3 conv (planar fws) -> writes d_out ---------
// block = (tile 16x32 px, group d, batch). wave-uniform oc-pair per wave.
__global__ __launch_bounds__(256) void k6a_dep(const u16* __restrict__ fws,
                                               const float* __restrict__ w_dep,
                                               const float* __restrict__ b_dep,
                                               float* __restrict__ out){
    int b = blockIdx.z, d = blockIdx.y;
    int ty = blockIdx.x / 5, tx = blockIdx.x % 5;
    int r0 = ty*16, c0 = tx*32;
    __shared__ u16 inl[9*18*36];
    __shared__ float wl[648];
    __shared__ float bb[8];
    int t = threadIdx.x;
    for (int i = t; i < 9*18*34; i += 256){
        int ch = i / 612, rem = i % 612, r = rem / 34, c = rem % 34;
        int gr = r0 + r - 1, gc = c0 + c - 1;
        u16 v = 0;
        if (gr >= 0 && gr < HT && gc >= 0 && gc < WD)
            v = fws[((size_t)(b*108 + d*9 + ch))*HW + gr*WD + gc];
        inl[ch*648 + r*36 + c] = v;
    }
    for (int i = t; i < 648; i += 256) wl[i] = w_dep[d*8*81 + i];
    if (t < 8) bb[t] = b_dep[d*8 + t];
    __syncthreads();
    int op = t >> 6, slot = t & 63;
    int rp = slot >> 3, cq = slot & 7;
    float acc[2][8];
    #pragma unroll
    for (int oo = 0; oo < 2; oo++){
        float bv = bb[op*2 + oo];
        #pragma unroll
        for (int p = 0; p < 8; p++) acc[oo][p] = bv;
    }
    #pragma unroll
    for (int ch = 0; ch < 9; ch++){
        float win[4][6];
        int base = ch*648 + rp*2*36 + cq*4;
        #pragma unroll
        for (int dr = 0; dr < 4; dr++)
            #pragma unroll
            for (int dc = 0; dc < 6; dc++)
                win[dr][dc] = bf2f(inl[base + dr*36 + dc]);
        #pragma unroll
        for (int oo = 0; oo < 2; oo++){
            const float* wp = &wl[((op*2 + oo)*9 + ch)*9];
            #pragma unroll
            for (int ki = 0; ki < 3; ki++)
                #pragma unroll
                for (int kj = 0; kj < 3; kj++){
                    float w = wp[ki*3 + kj];
                    #pragma unroll
                    for (int pr = 0; pr < 2; pr++)
                        #pragma unroll
                        for (int pc = 0; pc < 4; pc++)
                            acc[oo][pr*4+pc] += w * win[pr+ki][pc+kj];
                }
        }
    }
    #pragma unroll
    for (int oo = 0; oo < 2; oo++){
        int oc = d*8 + op*2 + oo;
        #pragma unroll
        for (int pr = 0; pr < 2; pr++){
            float4 v = make_float4(acc[oo][pr*4+0], acc[oo][pr*4+1],
                                   acc[oo][pr*4+2], acc[oo][pr*4+3]);
            *(float4*)(out + ((size_t)b*C + oc)*HW + (r0 + rp*2 + pr)*WD + c0 + cq*4) = v;
        }
    }
}

// ---------------- K6b: out += M[b] @ V (attention+proj epilogue) -------------
__global__ __launch_bounds__(256) void k6b_pv(const u16* __restrict__ qkv,
                                              const float* __restrict__ Mm,
                                              float* __restrict__ out){
    int b   = blockIdx.z;
    int co0 = blockIdx.y * 16;
    int px  = blockIdx.x * 1024 + threadIdx.x * 4;
    __shared__ float ms[16*96];
    for (int i = threadIdx.x; i < 16*96; i += 256)
        ms[i] = Mm[((size_t)b*C + co0)*C + i];
    __syncthreads();
    const u16* vb = qkv + ((size_t)b*C3 + 2*C)*HW + px;
    float* ob = out + ((size_t)b*C + co0)*HW + px;
    float acc[16][4];
    #pragma unroll
    for (int i = 0; i < 16; i++){
        float4 o4 = *(const float4*)(ob + (size_t)i*HW);
        acc[i][0]=o4.x; acc[i][1]=o4.y; acc[i][2]=o4.z; acc[i][3]=o4.w;
    }
    for (int c = 0; c < 96; c++){
        uint2 vv = *(const uint2*)(vb + (size_t)c*HW);
        float v0 = bf2f((u16)(vv.x & 0xffffu));
        float v1 = bf2f((u16)(vv.x >> 16));
        float v2 = bf2f((u16)(vv.y & 0xffffu));
        float v3 = bf2f((u16)(vv.y >> 16));
        #pragma unroll
        for (int i = 0; i < 16; i++){
            float w = ms[i*96 + c];
            acc[i][0] += w*v0; acc[i][1] += w*v1;
            acc[i][2] += w*v2; acc[i][3] += w*v3;
        }
    }
    #pragma unroll
    for (int i = 0; i < 16; i++)
        *(float4*)(ob + (size_t)i*HW) = make_float4(acc[i][0],acc[i][1],acc[i][2],acc[i][3]);
}

// -----------------------------------------------------------------------------
extern "C" void kernel_launch(void* const* d_in, const int* in_sizes, int n_in,
                              void* d_out, int out_size, void* d_ws, size_t ws_size,
                              hipStream_t stream){
    (void)in_sizes; (void)n_in; (void)out_size; (void)ws_size;
    const float* x           = (const float*)d_in[0];
    const float* spectral    = (const float*)d_in[1];
    const float* temperature = (const float*)d_in[2];
    const float* w_qkv       = (const float*)d_in[3];
    const float* w_dw        = (const float*)d_in[4];
    const float* w_proj      = (const float*)d_in[5];
    const float* w_fc        = (const float*)d_in[6];
    const float* b_fc        = (const float*)d_in[7];
    const float* w_dep       = (const float*)d_in[8];
    const float* b_dep       = (const float*)d_in[9];
    const float* w_se1       = (const float*)d_in[10];
    const float* b_se1       = (const float*)d_in[11];
    const float* w_se2       = (const float*)d_in[12];
    const float* b_se2       = (const float*)d_in[13];
    const float* w_saw1      = (const float*)d_in[14];
    const float* b_saw1      = (const float*)d_in[15];
    const float* w_saw2      = (const float*)d_in[16];
    const float* b_saw2      = (const float*)d_in[17];
    const float* w_sgp       = (const float*)d_in[18];
    const float* b_sgp       = (const float*)d_in[19];
    float* out = (float*)d_out;
    char* ws   = (char*)d_ws;

    // workspace layout (~116.6 MB)
    u16*   qkv = (u16*)ws;                          // 58,982,400 B
    u16*   Y   = (u16*)(ws + 58982400ull);          // 14,745,600 B (1 batch)
    u16*   fws = (u16*)(ws + 73728000ull);          // 22,118,400 B
    u16*   xb  = (u16*)(ws + 95846400ull);          // 19,660,800 B
    float* sm  = (float*)(ws + 115507200ull);       // small fp32 pool
    float* xsum  = sm;            // 384
    float* swg   = sm + 384;      // 384
    float* esgg  = sm + 768;      // 384
    float* weff  = sm + 1152;     // 110,592
    float* Mm    = sm + 111744;   // 36,864
    float* gpart = sm + 148608;   // 134,400

    k0_xsum <<<dim3(NB*C),     dim3(256), 0, stream>>>(x, xsum, xb);
    k1_small<<<dim3(1),        dim3(256), 0, stream>>>(spectral, xsum,
                w_se1, b_se1, w_se2, b_se2, w_saw1, b_saw1, w_saw2, b_saw2,
                w_sgp, b_sgp, w_qkv, swg, esgg, weff);
    for (int b = 0; b < NB; b++){
        k2a_qkv <<<dim3(25,12), dim3(256), 0, stream>>>(xb, weff, Y, b);
        k2b_dw  <<<dim3(20,C3), dim3(256), 0, stream>>>(Y, w_dw, qkv, b);
    }
    k3_fc   <<<dim3(800,NB),   dim3(256), 0, stream>>>(qkv, w_fc, b_fc, fws);
    k4_gram <<<dim3(25,NH,NB), dim3(256), 0, stream>>>(qkv, gpart);
    k5_attn <<<dim3(NB),       dim3(256), 0, stream>>>(gpart, esgg, temperature, w_proj, Mm);
    k6a_dep <<<dim3(50,12,NB), dim3(256), 0, stream>>>(fws, w_dep, b_dep, out);
    k6b_pv  <<<dim3(25,6,NB),  dim3(256), 0, stream>>>(qkv, Mm, out);
}

// Round 4
// 313.942 us; speedup vs baseline: 1.6797x; 1.6797x over previous
//
#include <hip/hip_runtime.h>
#include <math.h>

#define NB 4
#define C 96
#define C3 288
#define NH 8
#define CHD 12
#define HT 160
#define WD 160
#define HW 25600

typedef unsigned short u16;
typedef unsigned int   u32;
typedef __bf16 bf16x8 __attribute__((ext_vector_type(8)));
typedef float  f32x4  __attribute__((ext_vector_type(4)));

__device__ __forceinline__ float gelu_f(float x){
    return 0.5f * x * (1.0f + erff(x * 0.7071067811865475f));
}
__device__ __forceinline__ float sigmoid_f(float x){
    return 1.0f / (1.0f + expf(-x));
}
__device__ __forceinline__ u16 f2bf(float x){
    union { float f; u32 u; } v; v.f = x;
    u32 r = v.u + 0x7FFFu + ((v.u >> 16) & 1u);
    return (u16)(r >> 16);
}
__device__ __forceinline__ float bf2f(u16 s){
    union { u32 u; float f; } v; v.u = ((u32)s) << 16;
    return v.f;
}

// ---------------- K0: per-(b,c) spatial sums of x + bf16 copy of x ----------
__global__ __launch_bounds__(256) void k0_xsum(const float* __restrict__ x,
                                               float* __restrict__ xsum,
                                               u16* __restrict__ xb){
    int bc = blockIdx.x;                       // 0..383
    const float4* p4 = (const float4*)(x + (size_t)bc * HW);
    u32* xo = (u32*)(xb + (size_t)bc * HW);
    float s = 0.f;
    for (int i = threadIdx.x; i < HW/4; i += 256){
        float4 v = p4[i];
        s += (v.x + v.y) + (v.z + v.w);
        xo[i*2]   = (u32)f2bf(v.x) | ((u32)f2bf(v.y) << 16);
        xo[i*2+1] = (u32)f2bf(v.z) | ((u32)f2bf(v.w) << 16);
    }
    __shared__ float red[256];
    red[threadIdx.x] = s;
    __syncthreads();
    for (int off = 128; off > 0; off >>= 1){
        if (threadIdx.x < off) red[threadIdx.x] += red[threadIdx.x + off];
        __syncthreads();
    }
    if (threadIdx.x == 0) xsum[bc] = red[0];
}

// ---------------- K1: per-batch tiny math (one block per batch) --------------
__global__ void k1_small(const float* __restrict__ spectral, const float* __restrict__ xsum,
                         const float* __restrict__ w_se1, const float* __restrict__ b_se1,
                         const float* __restrict__ w_se2, const float* __restrict__ b_se2,
                         const float* __restrict__ w_saw1, const float* __restrict__ b_saw1,
                         const float* __restrict__ w_saw2, const float* __restrict__ b_saw2,
                         const float* __restrict__ w_sgp, const float* __restrict__ b_sgp,
                         float* __restrict__ swg, float* __restrict__ esgg){
    __shared__ float spec[96];
    __shared__ float h1[192];
    __shared__ float cm_s;
    __shared__ float g1[9][24];
    __shared__ float saw[8];
    __shared__ float redbuf[96];
    int t = threadIdx.x;
    int b = blockIdx.x;
    if (t < 96) spec[t] = spectral[b*96 + t];
    __syncthreads();
    if (t < 192){
        float a = b_se1[t];
        for (int c = 0; c < 96; c++) a += spec[c] * w_se1[t*96 + c];
        h1[t] = gelu_f(a);
    }
    __syncthreads();
    if (t < 96){
        float a = b_se2[t];
        for (int j = 0; j < 192; j++) a += h1[j] * w_se2[t*192 + j];
        float s = sigmoid_f(a);
        swg[b*96 + t] = s;
        redbuf[t] = s * xsum[b*96 + t];
    }
    __syncthreads();
    if (t == 0){
        float cs = 0.f;
        for (int c = 0; c < 96; c++) cs += redbuf[c];
        cm_s = cs / (96.0f * (float)HW);
    }
    __syncthreads();
    float cm = cm_s;
    if (t < 9*24){
        int cat = t / 24, ch = t % 24;
        int ti = cat / 3, tj = cat % 3;
        float S = 0.f;
        for (int ki = 0; ki < 3; ki++){
            if (ti == 0 && ki == 0) continue;
            if (ti == 2 && ki == 2) continue;
            for (int kj = 0; kj < 3; kj++){
                if (tj == 0 && kj == 0) continue;
                if (tj == 2 && kj == 2) continue;
                S += w_saw1[ch*9 + ki*3 + kj];
            }
        }
        g1[cat][ch] = gelu_f(cm * S + b_saw1[ch]);
    }
    __syncthreads();
    if (t < 8){
        float acc = 0.f;
        const float cnt[3] = {1.f, 158.f, 1.f};
        for (int cat = 0; cat < 9; cat++){
            float a = b_saw2[t];
            for (int ch = 0; ch < 24; ch++) a += w_saw2[t*24 + ch] * g1[cat][ch];
            acc += cnt[cat/3] * cnt[cat%3] * sigmoid_f(a);
        }
        saw[t] = acc / (float)HW;
    }
    __syncthreads();
    if (t < 96){
        float a = b_sgp[t];
        for (int j = 0; j < 96; j++) a += spec[j] * w_sgp[t*96 + j];
        esgg[b*96 + t] = a * saw[t/12];
    }
}

// ---------------- K2a: MFMA 1x1 conv: Y[oc,px] = (w_qkv*sw) @ xb -------------
// BM=96 (6 waves x 16 oc), BN=64 px, K=96 fully staged in LDS.
__global__ __launch_bounds__(384) void k2a_mfma(const u16* __restrict__ xb,
                                                const float* __restrict__ w_qkv,
                                                const float* __restrict__ swg,
                                                u16* __restrict__ Y,
                                                int bbase, long ystride){
    int b   = bbase + blockIdx.z;
    int oc0 = blockIdx.y * 96;
    int px0 = blockIdx.x * 64;
    __shared__ u16 Wl[96*104];
    __shared__ u16 Xl[64*104];
    int t = threadIdx.x;
    // stage W (96 oc x 96 c), scaled by spectral gate sw[c], converted to bf16
    for (int i = t; i < 96*96; i += 384){
        int r = i / 96, c = i % 96;
        float w = w_qkv[(oc0 + r)*96 + c] * swg[b*96 + c];
        Wl[r*104 + c] = f2bf(w);
    }
    // stage X tile (96 c x 64 px), transposed to Xl[px][c]
    const u32* xsrc = (const u32*)(xb + (size_t)b*C*HW + px0);
    for (int i = t; i < 96*32; i += 384){
        int c = i / 32, pq = i % 32;
        u32 v = xsrc[(size_t)c*(HW/2) + pq];
        Xl[(2*pq)*104 + c]   = (u16)(v & 0xffffu);
        Xl[(2*pq+1)*104 + c] = (u16)(v >> 16);
    }
    __syncthreads();
    int wid = t >> 6, lane = t & 63;
    int lr = lane & 15, lk = lane >> 4;          // lk in 0..3
    union U { uint4 q; bf16x8 v; };
    bf16x8 afr[3];
    #pragma unroll
    for (int kk = 0; kk < 3; kk++){
        U u; u.q = *(const uint4*)(&Wl[(wid*16 + lr)*104 + kk*32 + lk*8]);
        afr[kk] = u.v;
    }
    f32x4 acc[4];
    #pragma unroll
    for (int s = 0; s < 4; s++) acc[s] = (f32x4){0.f,0.f,0.f,0.f};
    #pragma unroll
    for (int sub = 0; sub < 4; sub++){
        #pragma unroll
        for (int kk = 0; kk < 3; kk++){
            U u; u.q = *(const uint4*)(&Xl[(sub*16 + lr)*104 + kk*32 + lk*8]);
            acc[sub] = __builtin_amdgcn_mfma_f32_16x16x32_bf16(afr[kk], u.v, acc[sub], 0, 0, 0);
        }
    }
    // D: col(px) = lane&15, row(oc) = (lane>>4)*4 + reg
    u16* Yb = Y + (size_t)blockIdx.z * ystride;
    #pragma unroll
    for (int sub = 0; sub < 4; sub++){
        #pragma unroll
        for (int r = 0; r < 4; r++){
            int oc = oc0 + wid*16 + lk*4 + r;
            Yb[(size_t)oc*HW + px0 + sub*16 + lr] = f2bf(acc[sub][r]);
        }
    }
}

// ---------------- K2b: 3x3 depthwise, Y bf16 -> qkv bf16 (padded cols) -------
__global__ __launch_bounds__(256) void k2b_dw(const u16* __restrict__ Y,
                                              const float* __restrict__ w_dw,
                                              u16* __restrict__ qkv,
                                              int bbase, long ystride){
    int b  = bbase + blockIdx.z;
    int ch = blockIdx.y;
    int r0 = blockIdx.x * 8;
    __shared__ float tile[10*162];
    const u16* Yc = Y + (size_t)blockIdx.z*ystride + (size_t)ch*HW;
    int t = threadIdx.x;
    if (t < 10){ tile[t*162] = 0.f; tile[t*162 + 161] = 0.f; }
    for (int i = t; i < 800; i += 256){
        int r = i / 80, c2 = (i % 80) * 2;
        int gr = r0 + r - 1;
        u32 v = 0;
        if (gr >= 0 && gr < HT) v = *(const u32*)(Yc + gr*WD + c2);
        tile[r*162 + 1 + c2] = bf2f((u16)(v & 0xffffu));
        tile[r*162 + 2 + c2] = bf2f((u16)(v >> 16));
    }
    float w[9];
    #pragma unroll
    for (int k = 0; k < 9; k++) w[k] = w_dw[ch*9 + k];
    __syncthreads();
    u16* qc = qkv + ((size_t)b*C3 + ch)*HW + r0*WD;
    for (int i = t; i < 640; i += 256){
        int r = i / 80, c2 = (i % 80) * 2;
        float a0 = 0.f, a1 = 0.f;
        #pragma unroll
        for (int ki = 0; ki < 3; ki++){
            const float* row = &tile[(r+ki)*162 + c2];
            #pragma unroll
            for (int kj = 0; kj < 3; kj++){
                float wv = w[ki*3+kj];
                a0 += wv * row[kj];
                a1 += wv * row[kj+1];
            }
        }
        u32 pk = (u32)f2bf(a0) | ((u32)f2bf(a1) << 16);
        *(u32*)(qc + r*WD + c2) = pk;
    }
}

// ---------------- K3: fc branch -> fws PLANAR (b,108,hw) bf16 ----------------
__global__ __launch_bounds__(256) void k3_fc(const u16* __restrict__ qkv,
                                             const float* __restrict__ w_fc,
                                             const float* __restrict__ b_fc,
                                             u16* __restrict__ fws){
    int b  = blockIdx.y;
    int n0 = blockIdx.x * 32;
    __shared__ u16 r[32*289];
    __shared__ u16 ot[108*33];
    __shared__ float wfc[216];
    __shared__ float bfc[9];
    int t = threadIdx.x;
    if (t < 216) wfc[t] = w_fc[t];
    if (t < 9)   bfc[t] = b_fc[t];
    const u32* src = (const u32*)(qkv + (size_t)b*C3*HW + (size_t)n0*288);
    for (int i = t; i < 32*144; i += 256){
        u32 v = src[i];
        int row = i / 144, cc = (i % 144) * 2;
        r[row*289 + cc]     = (u16)(v & 0xffffu);
        r[row*289 + cc + 1] = (u16)(v >> 16);
    }
    __syncthreads();
    for (int col = t; col < 384; col += 256){
        int nl = col / 12, d = col % 12;
        float rv[24];
        #pragma unroll
        for (int g = 0; g < 24; g++) rv[g] = bf2f(r[nl*289 + g*12 + d]);
        #pragma unroll
        for (int o = 0; o < 9; o++){
            float a = bfc[o];
            #pragma unroll
            for (int g = 0; g < 24; g++) a += wfc[o*24 + g] * rv[g];
            ot[(d*9 + o)*33 + nl] = f2bf(a);
        }
    }
    __syncthreads();
    for (int i = t; i < 108*16; i += 256){
        int pl = i / 16, p2 = (i % 16) * 2;
        u32 pk = (u32)ot[pl*33 + p2] | ((u32)ot[pl*33 + p2 + 1] << 16);
        *(u32*)(fws + ((size_t)(b*108 + pl))*HW + n0 + p2) = pk;
    }
}

// ---------------- K4: Gram partials G[c,d]=sum_n q_c k_d, plus norms ---------
__global__ __launch_bounds__(256) void k4_gram(const u16* __restrict__ qkv,
                                               float* __restrict__ gpart){
    int b = blockIdx.z;
    int h = blockIdx.y;
    int t = threadIdx.x;
    __shared__ float qs[12*268];
    __shared__ float ks[12*268];
    const u32* qu = (const u32*)(qkv + ((size_t)b*C3 + h*CHD)*HW + blockIdx.x*1024);
    const u32* ku = (const u32*)(qkv + ((size_t)b*C3 + C + h*CHD)*HW + blockIdx.x*1024);
    float acc = 0.f;
    for (int sc = 0; sc < 4; sc++){
        __syncthreads();
        for (int i = t; i < 12*128; i += 256){
            int rr = i / 128, pu = i % 128;
            u32 qv = qu[rr*(HW/2) + sc*128 + pu];
            u32 kv = ku[rr*(HW/2) + sc*128 + pu];
            qs[rr*268 + 2*pu]     = bf2f((u16)(qv & 0xffffu));
            qs[rr*268 + 2*pu + 1] = bf2f((u16)(qv >> 16));
            ks[rr*268 + 2*pu]     = bf2f((u16)(kv & 0xffffu));
            ks[rr*268 + 2*pu + 1] = bf2f((u16)(kv >> 16));
        }
        __syncthreads();
        if (t < 144){
            int c = t / 12, d = t % 12;
            const float* qq = &qs[c*268];
            const float* kk = &ks[d*268];
            float a = 0.f;
            for (int p = 0; p < 256; p += 4){
                float4 q4 = *(const float4*)(qq + p);
                float4 k4 = *(const float4*)(kk + p);
                a += q4.x*k4.x + q4.y*k4.y + q4.z*k4.z + q4.w*k4.w;
            }
            acc += a;
        } else if (t < 168){
            int c = (t - 144) % 12;
            const float* qq = (t < 156) ? &qs[c*268] : &ks[c*268];
            float a = 0.f;
            for (int p = 0; p < 256; p += 4){
                float4 q4 = *(const float4*)(qq + p);
                a += q4.x*q4.x + q4.y*q4.y + q4.z*q4.z + q4.w*q4.w;
            }
            acc += a;
        }
    }
    if (t < 168)
        gpart[(((size_t)b*NH + h)*25 + blockIdx.x)*168 + t] = acc;
}

// ---------------- K5: softmax + M[b] = W_proj @ blockdiag(attn) --------------
__global__ void k5_attn(const float* __restrict__ gpart, const float* __restrict__ esgg,
                        const float* __restrict__ temp, const float* __restrict__ w_proj,
                        float* __restrict__ Mm){
    int b = blockIdx.x;
    int t = threadIdx.x;
    __shared__ float G[NH][144];
    __shared__ float q2[NH][12], k2[NH][12];
    __shared__ float attn[NH][144];
    for (int i = t; i < NH*168; i += 256){
        int h = i / 168, e = i % 168;
        float a = 0.f;
        for (int ch = 0; ch < 25; ch++)
            a += gpart[(((size_t)b*NH + h)*25 + ch)*168 + e];
        if (e < 144)      G[h][e] = a;
        else if (e < 156) q2[h][e-144] = a;
        else              k2[h][e-156] = a;
    }
    __syncthreads();
    if (t < 96){
        int h = t / 12, c = t % 12;
        float rq  = 1.0f / fmaxf(sqrtf(q2[h][c]), 1e-12f);
        float tm  = temp[h];
        float egc = esgg[b*96 + h*12 + c];
        float lo[12];
        float mx = -1e30f;
        for (int d = 0; d < 12; d++){
            float rk = 1.0f / fmaxf(sqrtf(k2[h][d]), 1e-12f);
            float v = G[h][c*12 + d] * rq * rk * tm * (egc * esgg[b*96 + h*12 + d]);
            lo[d] = v;
            mx = fmaxf(mx, v);
        }
        float s = 0.f;
        for (int d = 0; d < 12; d++){ lo[d] = expf(lo[d] - mx); s += lo[d]; }
        float inv = 1.0f / s;
        for (int d = 0; d < 12; d++) attn[h][c*12 + d] = lo[d] * inv;
    }
    __syncthreads();
    for (int i = t; i < 96*96; i += 256){
        int co = i / 96, ci = i % 96;
        int h = ci / 12, d = ci % 12;
        float a = 0.f;
        #pragma unroll
        for (int c = 0; c < 12; c++)
            a += w_proj[co*96 + h*12 + c] * attn[h][c*12 + d];
        Mm[((size_t)b*96 + co)*96 + ci] = a;
    }
}

// ---------------- K6a: grouped 3x3 conv (planar fws) -> writes d_out ---------
__global__ __launch_bounds__(256) void k6a_dep(const u16* __restrict__ fws,
                                               const float* __restrict__ w_dep,
                                               const float* __restrict__ b_dep,
                                               float* __restrict__ out){
    int b = blockIdx.z, d = blockIdx.y;
    int ty = blockIdx.x / 5, tx = blockIdx.x % 5;
    int r0 = ty*16, c0 = tx*32;
    __shared__ u16 inl[9*18*36];
    __shared__ float wl[648];
    __shared__ float bb[8];
    int t = threadIdx.x;
    for (int i = t; i < 9*18*34; i += 256){
        int ch = i / 612, rem = i % 612, r = rem / 34, c = rem % 34;
        int gr = r0 + r - 1, gc = c0 + c - 1;
        u16 v = 0;
        if (gr >= 0 && gr < HT && gc >= 0 && gc < WD)
            v = fws[((size_t)(b*108 + d*9 + ch))*HW + gr*WD + gc];
        inl[ch*648 + r*36 + c] = v;
    }
    for (int i = t; i < 648; i += 256) wl[i] = w_dep[d*8*81 + i];
    if (t < 8) bb[t] = b_dep[d*8 + t];
    __syncthreads();
    int op = t >> 6, slot = t & 63;
    int rp = slot >> 3, cq = slot & 7;
    float acc[2][8];
    #pragma unroll
    for (int oo = 0; oo < 2; oo++){
        float bv = bb[op*2 + oo];
        #pragma unroll
        for (int p = 0; p < 8; p++) acc[oo][p] = bv;
    }
    #pragma unroll
    for (int ch = 0; ch < 9; ch++){
        float win[4][6];
        int base = ch*648 + rp*2*36 + cq*4;
        #pragma unroll
        for (int dr = 0; dr < 4; dr++)
            #pragma unroll
            for (int dc = 0; dc < 6; dc++)
                win[dr][dc] = bf2f(inl[base + dr*36 + dc]);
        #pragma unroll
        for (int oo = 0; oo < 2; oo++){
            const float* wp = &wl[((op*2 + oo)*9 + ch)*9];
            #pragma unroll
            for (int ki = 0; ki < 3; ki++)
                #pragma unroll
                for (int kj = 0; kj < 3; kj++){
                    float w = wp[ki*3 + kj];
                    #pragma unroll
                    for (int pr = 0; pr < 2; pr++)
                        #pragma unroll
                        for (int pc = 0; pc < 4; pc++)
                            acc[oo][pr*4+pc] += w * win[pr+ki][pc+kj];
                }
        }
    }
    #pragma unroll
    for (int oo = 0; oo < 2; oo++){
        int oc = d*8 + op*2 + oo;
        #pragma unroll
        for (int pr = 0; pr < 2; pr++){
            float4 v = make_float4(acc[oo][pr*4+0], acc[oo][pr*4+1],
                                   acc[oo][pr*4+2], acc[oo][pr*4+3]);
            *(float4*)(out + ((size_t)b*C + oc)*HW + (r0 + rp*2 + pr)*WD + c0 + cq*4) = v;
        }
    }
}

// ---------------- K6b: out += M[b] @ V (attention+proj epilogue) -------------
__global__ __launch_bounds__(256) void k6b_pv(const u16* __restrict__ qkv,
                                              const float* __restrict__ Mm,
                                              float* __restrict__ out){
    int b   = blockIdx.z;
    int co0 = blockIdx.y * 16;
    int px  = blockIdx.x * 1024 + threadIdx.x * 4;
    __shared__ float ms[16*96];
    for (int i = threadIdx.x; i < 16*96; i += 256)
        ms[i] = Mm[((size_t)b*C + co0)*C + i];
    __syncthreads();
    const u16* vb = qkv + ((size_t)b*C3 + 2*C)*HW + px;
    float* ob = out + ((size_t)b*C + co0)*HW + px;
    float acc[16][4];
    #pragma unroll
    for (int i = 0; i < 16; i++){
        float4 o4 = *(const float4*)(ob + (size_t)i*HW);
        acc[i][0]=o4.x; acc[i][1]=o4.y; acc[i][2]=o4.z; acc[i][3]=o4.w;
    }
    for (int c = 0; c < 96; c++){
        uint2 vv = *(const uint2*)(vb + (size_t)c*HW);
        float v0 = bf2f((u16)(vv.x & 0xffffu));
        float v1 = bf2f((u16)(vv.x >> 16));
        float v2 = bf2f((u16)(vv.y & 0xffffu));
        float v3 = bf2f((u16)(vv.y >> 16));
        #pragma unroll
        for (int i = 0; i < 16; i++){
            float w = ms[i*96 + c];
            acc[i][0] += w*v0; acc[i][1] += w*v1;
            acc[i][2] += w*v2; acc[i][3] += w*v3;
        }
    }
    #pragma unroll
    for (int i = 0; i < 16; i++)
        *(float4*)(ob + (size_t)i*HW) = make_float4(acc[i][0],acc[i][1],acc[i][2],acc[i][3]);
}

// -----------------------------------------------------------------------------
extern "C" void kernel_launch(void* const* d_in, const int* in_sizes, int n_in,
                              void* d_out, int out_size, void* d_ws, size_t ws_size,
                              hipStream_t stream){
    (void)in_sizes; (void)n_in; (void)out_size;
    const float* x           = (const float*)d_in[0];
    const float* spectral    = (const float*)d_in[1];
    const float* temperature = (const float*)d_in[2];
    const float* w_qkv       = (const float*)d_in[3];
    const float* w_dw        = (const float*)d_in[4];
    const float* w_proj      = (const float*)d_in[5];
    const float* w_fc        = (const float*)d_in[6];
    const float* b_fc        = (const float*)d_in[7];
    const float* w_dep       = (const float*)d_in[8];
    const float* b_dep       = (const float*)d_in[9];
    const float* w_se1       = (const float*)d_in[10];
    const float* b_se1       = (const float*)d_in[11];
    const float* w_se2       = (const float*)d_in[12];
    const float* b_se2       = (const float*)d_in[13];
    const float* w_saw1      = (const float*)d_in[14];
    const float* b_saw1      = (const float*)d_in[15];
    const float* w_saw2      = (const float*)d_in[16];
    const float* b_saw2      = (const float*)d_in[17];
    const float* w_sgp       = (const float*)d_in[18];
    const float* b_sgp       = (const float*)d_in[19];
    float* out = (float*)d_out;
    char* ws   = (char*)d_ws;

    const size_t QKV_B = 58982400ull;   // 4*288*25600 bf16
    const size_t FWS_B = 22118400ull;   // 4*108*25600 bf16
    const size_t XB_B  = 19660800ull;   // 4*96*25600 bf16
    const size_t SM_B  = 1000000ull;
    const size_t Y_ONE = 14745600ull;   // 288*25600 bf16 (one batch)
    // Path A (batch-parallel k2) needs full Y; fall back to per-batch loop.
    bool fullY = ws_size >= QKV_B + 4*Y_ONE + FWS_B + XB_B + SM_B;
    size_t ybytes = fullY ? 4*Y_ONE : Y_ONE;

    u16*   qkv = (u16*)ws;
    u16*   Y   = (u16*)(ws + QKV_B);
    u16*   fws = (u16*)(ws + QKV_B + ybytes);
    u16*   xb  = (u16*)(ws + QKV_B + ybytes + FWS_B);
    float* sm  = (float*)(ws + QKV_B + ybytes + FWS_B + XB_B);
    float* xsum  = sm;            // 384
    float* swg   = sm + 384;      // 384
    float* esgg  = sm + 768;      // 384
    float* Mm    = sm + 1152;     // 36,864
    float* gpart = sm + 38016;    // 134,400

    k0_xsum <<<dim3(NB*C), dim3(256), 0, stream>>>(x, xsum, xb);
    k1_small<<<dim3(NB),   dim3(256), 0, stream>>>(spectral, xsum,
                w_se1, b_se1, w_se2, b_se2, w_saw1, b_saw1, w_saw2, b_saw2,
                w_sgp, b_sgp, swg, esgg);
    if (fullY){
        k2a_mfma<<<dim3(400,3,NB), dim3(384), 0, stream>>>(xb, w_qkv, swg, Y, 0, (long)C3*HW);
        k2b_dw  <<<dim3(20,C3,NB), dim3(256), 0, stream>>>(Y, w_dw, qkv, 0, (long)C3*HW);
    } else {
        for (int b = 0; b < NB; b++){
            k2a_mfma<<<dim3(400,3,1), dim3(384), 0, stream>>>(xb, w_qkv, swg, Y, b, 0);
            k2b_dw  <<<dim3(20,C3,1), dim3(256), 0, stream>>>(Y, w_dw, qkv, b, 0);
        }
    }
    k3_fc   <<<dim3(800,NB),   dim3(256), 0, stream>>>(qkv, w_fc, b_fc, fws);
    k4_gram <<<dim3(25,NH,NB), dim3(256), 0, stream>>>(qkv, gpart);
    k5_attn <<<dim3(NB),       dim3(256), 0, stream>>>(gpart, esgg, temperature, w_proj, Mm);
    k6a_dep <<<dim3(50,12,NB), dim3(256), 0, stream>>>(fws, w_dep, b_dep, out);
    k6b_pv  <<<dim3(25,6,NB),  dim3(256), 0, stream>>>(qkv, Mm, out);
}